// Round 14
// baseline (146.174 us; speedup 1.0000x reference)
//
#include <hip/hip_runtime.h>
#include <math.h>

#define B_ 8
#define N_ 224
#define E_ 64
#define M_ 128
#define S_ 32
#define D_ 256
#define IN_ 300
#define R_ 5
#define H_ 4
#define DK_ 64
#define OUTROWS (N_ + 2 * E_ * E_)   // 8416
#define CAP_ 192
#define BN_ (B_ * N_)                // 1792

typedef __attribute__((ext_vector_type(8))) short bf16x8;
typedef __attribute__((ext_vector_type(8))) unsigned short u16x8;
typedef __attribute__((ext_vector_type(4))) float f32x4;

__device__ inline short f2bf(float f) {
    union { float f; unsigned u; } x; x.f = f;
    unsigned u = x.u;
    unsigned r = (u + 0x7fffu + ((u >> 16) & 1u)) >> 16;
    return (short)r;
}
__device__ inline float bf2f(unsigned short s) {
    union { unsigned u; float f; } x; x.u = ((unsigned)s) << 16; return x.f;
}

// async global -> LDS, 16B per lane; lds base must be wave-uniform
__device__ inline void gload16(const void* g, void* l) {
    __builtin_amdgcn_global_load_lds(
        (const __attribute__((address_space(1))) unsigned int*)g,
        (__attribute__((address_space(3))) unsigned int*)l, 16, 0, 0);
}

// ================= mega preprocessing kernel (block-range dispatch) =================
#define PRE_PACK 1376
#define PRE_EDGE (PRE_PACK + BN_)     // 3168
#define PRE_ML   (PRE_EDGE + 2)       // 3170
#define CVT_N    573440               // 1792*320
#define CVT_M    262144               // 1024*256
#define CVT_S    262144               // msr
#define CVT_Q    131072               // WQs straight bf16 copy of Wq_h,Wq_t
#define PRE_TOT  (PRE_ML + 1200)      // 1200*1024 = 1,228,800 cvt elems

__global__ __launch_bounds__(256) void mega_pre(
    short* __restrict__ Wb,
    const float* Wr0, const float* W00, const float* Wr1, const float* W01,
    const float* Wkh, const float* Wkt, const float* Wvh, const float* Wvt,
    const float* Wqh, const float* Wqt, const float* Woh, const float* Wot,
    const float* __restrict__ adj, int* __restrict__ ecnt, int* __restrict__ elist,
    float* __restrict__ evals, float* __restrict__ den,
    const int* __restrict__ eid, int* __restrict__ mcnt, int* __restrict__ mlist,
    const float* __restrict__ nodes, const float* __restrict__ mentions,
    const float* __restrict__ sentences, const int* __restrict__ sid,
    short* __restrict__ nodesb, short* __restrict__ mentb, short* __restrict__ msrb,
    short* __restrict__ WQs) {
    __shared__ int smemi[528];
    __shared__ int wtot[4];
    __shared__ float wsum[4];
    int blk = blockIdx.x, tid = threadIdx.x;

    if (blk < PRE_PACK) {
        // ---- weight pack: bf16 transposed [n][k], 32x32 LDS transpose ----
        short (*T)[33] = (short(*)[33])smemi;
        int t = blk;
        const float* src; short* outp; int outld, klim, n0, k0;
        if (t < 480) {
            int z = t / 80, tt = t % 80;
            n0 = (tt & 7) * 32; k0 = (tt >> 3) * 32;
            outp = Wb + (size_t)z * 81920; outld = 320; klim = IN_;
            src = (z < 5) ? Wr0 + (size_t)z * IN_ * D_ : W00;
        } else if (t < 864) {
            int l = t - 480, z = l / 64, tt = l % 64;
            n0 = (tt & 7) * 32; k0 = (tt >> 3) * 32;
            outp = Wb + 491520 + (size_t)z * 65536; outld = 256; klim = 256;
            src = (z < 5) ? Wr1 + (size_t)z * D_ * D_ : W01;
        } else if (t < 992) {
            int l = t - 864, z = l / 64, tt = l % 64;
            n0 = (tt & 7) * 32; k0 = (tt >> 3) * 32;
            outp = Wb + 884736 + (size_t)z * 65536; outld = 256; klim = 256;
            src = z ? Wkt : Wkh;
        } else if (t < 1120) {
            int l = t - 992, z = l / 64, tt = l % 64;
            n0 = (tt & 7) * 32; k0 = (tt >> 3) * 32;
            outp = Wb + 1146880 + (size_t)z * 65536; outld = 256; klim = 256;
            src = z ? Wvt : Wvh;
        } else if (t < 1248) {
            int l = t - 1120, z = l / 64, tt = l % 64;
            n0 = (tt & 7) * 32; k0 = (tt >> 3) * 32;
            outp = Wb + 1409024 + (size_t)z * 65536; outld = 256; klim = 256;
            src = z ? Wqt : Wqh;
        } else {
            int l = t - 1248, z = l / 16, tt = l % 16;
            n0 = (tt & 7) * 32; k0 = (tt >> 3) * 32;
            outp = Wb + 1671168 + (size_t)z * 16384; outld = 64; klim = 64;
            int which = z >> 2, h = z & 3;
            src = (which ? Wot : Woh) + (size_t)(h * 64) * D_;
        }
        int tx = tid & 31, ty = tid >> 5;
#pragma unroll
        for (int i = 0; i < 4; ++i) {
            int k = k0 + ty + 8 * i;
            float v = (k < klim) ? src[(size_t)k * D_ + n0 + tx] : 0.f;
            T[tx][ty + 8 * i] = f2bf(v);
        }
        __syncthreads();
#pragma unroll
        for (int i = 0; i < 4; ++i) {
            int n = ty + 8 * i;
            outp[(size_t)(n0 + n) * outld + k0 + tx] = T[n][tx];
        }
    } else if (blk < PRE_EDGE) {
        // ---- edge lists + denoms: shfl-scan; XCD-swizzled so batch b -> one XCD ----
        int local = blk - PRE_PACK;
        int bn = (local & 7) * N_ + (local >> 3);
        int b = bn / N_, n = bn % N_;
        int lane = tid & 63, wv4 = tid >> 6;
        int idxs[5]; float vals[5];
        int cloc = 0; float sloc = 0.f;
        for (int e = tid; e < R_ * N_; e += 256) {
            int r = e / N_, m = e % N_;
            float v = adj[(((size_t)(b * R_ + r)) * N_ + n) * N_ + m];
            if (v != 0.f) { idxs[cloc] = r * BN_ + m; vals[cloc] = v; ++cloc; sloc += v; }
        }
        int v = cloc;
#pragma unroll
        for (int st = 1; st < 64; st <<= 1) {
            int o = __shfl_up(v, st, 64);
            if (lane >= st) v += o;
        }
        float fs = sloc;
#pragma unroll
        for (int st = 32; st > 0; st >>= 1) fs += __shfl_xor(fs, st, 64);
        if (lane == 63) wtot[wv4] = v;
        if (lane == 0)  wsum[wv4] = fs;
        __syncthreads();
        int woff = 0;
        for (int i = 0; i < wv4; ++i) woff += wtot[i];
        int off = woff + v - cloc;
        int total = wtot[0] + wtot[1] + wtot[2] + wtot[3];
        size_t base = (size_t)bn * CAP_;
        for (int i = 0; i < cloc; ++i) {
            int p = off + i;
            if (p < CAP_) { elist[base + p] = idxs[i]; evals[base + p] = vals[i]; }
        }
        if (tid == 0) {
            ecnt[bn] = total < CAP_ ? total : CAP_;
            den[bn] = wsum[0] + wsum[1] + wsum[2] + wsum[3] + 1.0f;
        }
    } else if (blk < PRE_ML) {
        int t = (blk - PRE_EDGE) * 256 + tid;
        if (t < B_ * E_) {
            int b = t / E_, i = t % E_;
            int c = 0;
            for (int m = 0; m < M_; ++m)
                if (eid[b * M_ + m] == i) mlist[(size_t)t * M_ + c++] = m;
            mcnt[t] = c;
        }
    } else {
        int idx = (blk - PRE_ML) * 1024 + tid * 4;
#pragma unroll
        for (int j = 0; j < 4; ++j) {
            int i = idx + j;
            if (i < CVT_N) {
                int row = i / 320, k = i % 320;
                nodesb[i] = (k < IN_) ? f2bf(nodes[(size_t)row * IN_ + k]) : (short)0;
            } else if (i < CVT_N + CVT_M) {
                int i2 = i - CVT_N;
                mentb[i2] = f2bf(mentions[i2]);
            } else if (i < CVT_N + CVT_M + CVT_S) {
                int i3 = i - CVT_N - CVT_M;
                int bm = i3 >> 8, d = i3 & 255;
                msrb[i3] = f2bf(sentences[(size_t)sid[bm] * D_ + d]);
            } else {
                int i4 = i - CVT_N - CVT_M - CVT_S;   // < 131072
                WQs[i4] = f2bf(i4 >= 65536 ? Wqt[i4 - 65536] : Wqh[i4]);
            }
        }
    }
}

// ---------- AxW via edge gather (bf16 xW), 4 gather-waves + LDS reduce ----------
// XCD-swizzled: bn = (bid%8)*N + bid/8 pins batch b to one XCD.
__global__ __launch_bounds__(256) void axw_gather(
    const short* __restrict__ xWb,
    const int* __restrict__ ecnt, const int* __restrict__ elist,
    const float* __restrict__ evals, const float* __restrict__ den,
    short* __restrict__ hb, float* __restrict__ out, long long out_bstride) {
    int bid = blockIdx.x;
    int bn = (bid & 7) * N_ + (bid >> 3);
    int b = bn / N_, n = bn % N_;
    int tid = threadIdx.x, wv = tid >> 6, dq = tid & 63;
    int c = ecnt[bn];
    int bno = b * N_;
    const int* lst = elist + (size_t)bn * CAP_;
    const float* vls = evals + (size_t)bn * CAP_;
    float4 acc = make_float4(0.f, 0.f, 0.f, 0.f);
#pragma unroll 2
    for (int k = wv; k < c; k += 4) {
        int rm = lst[k];
        float v = vls[k];
        ushort4 x4 = *(const ushort4*)&xWb[((size_t)(rm + bno)) * 256 + dq * 4];
        acc.x += v * bf2f(x4.x); acc.y += v * bf2f(x4.y);
        acc.z += v * bf2f(x4.z); acc.w += v * bf2f(x4.w);
    }
    __shared__ float4 red[4][64];
    red[wv][dq] = acc;
    __syncthreads();
    if (tid < 64) {
        float4 s0 = red[0][dq], s1 = red[1][dq], s2 = red[2][dq], s3 = red[3][dq];
        ushort4 t4 = *(const ushort4*)&xWb[((size_t)(5 * BN_ + bn)) * 256 + dq * 4];
        float inv = 1.f / den[bn];
        float4 o;
        o.x = fmaxf((s0.x + s1.x + s2.x + s3.x + bf2f(t4.x)) * inv, 0.f);
        o.y = fmaxf((s0.y + s1.y + s2.y + s3.y + bf2f(t4.y)) * inv, 0.f);
        o.z = fmaxf((s0.z + s1.z + s2.z + s3.z + bf2f(t4.z)) * inv, 0.f);
        o.w = fmaxf((s0.w + s1.w + s2.w + s3.w + bf2f(t4.w)) * inv, 0.f);
        if (hb) {
            ushort4 hw = { (unsigned short)f2bf(o.x), (unsigned short)f2bf(o.y),
                           (unsigned short)f2bf(o.z), (unsigned short)f2bf(o.w) };
            *(ushort4*)&hb[(size_t)bn * 256 + dq * 4] = hw;
        }
        if (out)
            *(float4*)&out[(size_t)b * out_bstride + (size_t)n * 256 + dq * 4] = o;
    }
}

// ---------- multi-GEMM: per-blockIdx.z descriptor, all-bf16, tile 64x64, BK=64 ----------
struct GDesc {
    const short* A; const short* Bt; short* C; const float* bias;
    int lda, ldbk, ldc, Kloop, ny;
};
struct GTable { GDesc d[22]; };

__global__ __launch_bounds__(256) void gemm_multi(GTable T) {
    GDesc g = T.d[blockIdx.z];
    if ((int)blockIdx.y >= g.ny) return;

    __shared__ short As[64 * 64];
    __shared__ short Bs[64 * 64];
    int tid = threadIdx.x;
    int lane = tid & 63, wv = tid >> 6;
    int wr = wv >> 1, wc = wv & 1;
    int fr = lane & 15;
    int so = lane >> 4;              // fragment slot sub-index (0..3)
    int row0 = blockIdx.y * 64, col0 = blockIdx.x * 64;

    // staging geometry: each wave stages chunks c0,c1 (1KB each = 8 rows x 128B)
    int l8 = lane >> 3;              // row within chunk (0..7)
    int sl = (lane & 7) ^ l8;        // pre-swizzled 16B slot
    int c0 = 2 * wv, c1 = c0 + 1;
    int ra0 = row0 + 8 * c0 + l8, ra1 = row0 + 8 * c1 + l8;
    int rb0 = col0 + 8 * c0 + l8, rb1 = col0 + 8 * c1 + l8;

    f32x4 acc00 = {0.f,0.f,0.f,0.f}, acc01 = acc00, acc10 = acc00, acc11 = acc00;

    int rA0 = wr * 32 + fr, rA1 = rA0 + 16;
    int rB0 = wc * 32 + fr, rB1 = rB0 + 16;
    int sw = fr & 7;

    for (int k0 = 0; k0 < g.Kloop; k0 += 64) {
        gload16(&g.A [(size_t)ra0 * g.lda  + k0 + sl * 8], &As[c0 * 512]);
        gload16(&g.A [(size_t)ra1 * g.lda  + k0 + sl * 8], &As[c1 * 512]);
        gload16(&g.Bt[(size_t)rb0 * g.ldbk + k0 + sl * 8], &Bs[c0 * 512]);
        gload16(&g.Bt[(size_t)rb1 * g.ldbk + k0 + sl * 8], &Bs[c1 * 512]);
        __syncthreads();
#pragma unroll
        for (int ks = 0; ks < 2; ++ks) {
            int s = ks * 4 + so;
            bf16x8 a0 = *(bf16x8*)&As[rA0 * 64 + ((s ^ sw) << 3)];
            bf16x8 a1 = *(bf16x8*)&As[rA1 * 64 + ((s ^ sw) << 3)];
            bf16x8 b0 = *(bf16x8*)&Bs[rB0 * 64 + ((s ^ sw) << 3)];
            bf16x8 b1 = *(bf16x8*)&Bs[rB1 * 64 + ((s ^ sw) << 3)];
            acc00 = __builtin_amdgcn_mfma_f32_16x16x32_bf16(a0, b0, acc00, 0, 0, 0);
            acc01 = __builtin_amdgcn_mfma_f32_16x16x32_bf16(a0, b1, acc01, 0, 0, 0);
            acc10 = __builtin_amdgcn_mfma_f32_16x16x32_bf16(a1, b0, acc10, 0, 0, 0);
            acc11 = __builtin_amdgcn_mfma_f32_16x16x32_bf16(a1, b1, acc11, 0, 0, 0);
        }
        __syncthreads();
    }

    int rbase = row0 + wr * 32 + (lane >> 4) * 4;
    int cbase = col0 + wc * 32 + fr;
    f32x4 accs[2][2] = {{acc00, acc01}, {acc10, acc11}};
#pragma unroll
    for (int mi = 0; mi < 2; ++mi) {
#pragma unroll
        for (int nj = 0; nj < 2; ++nj) {
            int cc = cbase + nj * 16;
            float bval = g.bias ? g.bias[cc] : 0.f;
#pragma unroll
            for (int r = 0; r < 4; ++r) {
                int cr = rbase + mi * 16 + r;
                g.C[(size_t)cr * g.ldc + cc] = f2bf(accs[mi][nj][r] + bval);
            }
        }
    }
}

// fp32 row (ents) . bf16 row (KQ), 256 elems
__device__ inline float dot256_f_bf(const float* e, const short* kq) {
    float dot = 0.f;
#pragma unroll
    for (int t8 = 0; t8 < 32; ++t8) {
        u16x8 kv = *(const u16x8*)(kq + t8 * 8);
        float4 e0 = *(const float4*)(e + t8 * 8);
        float4 e1 = *(const float4*)(e + t8 * 8 + 4);
        dot += e0.x * bf2f(kv[0]) + e0.y * bf2f(kv[1]) + e0.z * bf2f(kv[2]) + e0.w * bf2f(kv[3])
             + e1.x * bf2f(kv[4]) + e1.y * bf2f(kv[5]) + e1.z * bf2f(kv[6]) + e1.w * bf2f(kv[7]);
    }
    return dot;
}

// ------------- per (b, masked-entity, rep) attention combine: 64 q rows/block -------------
// 1D grid 1024, XCD-swizzled decode: g = bid%16 (g = z*8+b), me = bid/16.
// Scores via S[q,m,h] = ents_fp32[b][q] . KQ[z*4+h][b*M+m]  (Q projection folded
// into KQ = K @ Wq_headslice^T, computed in GEMM B).  ents read from out rows.
__global__ __launch_bounds__(256) void combine_kernel(
    const short* __restrict__ KQb, const short* __restrict__ VWb,
    const int* __restrict__ cnt, const int* __restrict__ mlist,
    float* __restrict__ out) {
    int bid = blockIdx.x;
    int g = bid & 15, me = bid >> 4;
    int b = g & 7, z = g >> 3;
    const short* VW = VWb + (size_t)z * (B_ * M_ * H_ * D_);
    const float* ents = out + (size_t)b * OUTROWS * D_;   // first E rows = entities
    int baserow = N_ + z * (E_ * E_);
    int tid = threadIdx.x;
    int dq = tid & 63;
    __shared__ float sVW[2][H_ * D_];
    __shared__ float sS[E_][H_][2];
    int c = cnt[b * E_ + me];
    const int* lst = mlist + (size_t)(b * E_ + me) * M_;

    if (c >= 1 && c <= 2) {
        for (int k = 0; k < c; ++k) {
            ushort4 v4 = *(const ushort4*)(VW + ((size_t)b * M_ + lst[k]) * (H_ * D_) + tid * 4);
            *(float4*)&sVW[k][tid * 4] =
                make_float4(bf2f(v4.x), bf2f(v4.y), bf2f(v4.z), bf2f(v4.w));
        }
        for (int e = tid; e < E_ * H_ * 2; e += 256) {
            int k = e & 1, hh = (e >> 1) & 3, ql = e >> 3;
            if (k < c) {
                const short* KQrow = KQb + ((size_t)(z * 4 + hh)) * (B_ * M_ * D_)
                                         + ((size_t)b * M_ + lst[k]) * D_;
                sS[ql][hh][k] = dot256_f_bf(ents + (size_t)ql * D_, KQrow) * 0.125f;
            }
        }
        __syncthreads();
        {   // softmax: one (ql,hh) per thread (256 = 64*4)
            int hh = tid & 3, ql = tid >> 2;
            float mx = sS[ql][hh][0];
            for (int k = 1; k < c; ++k) mx = fmaxf(mx, sS[ql][hh][k]);
            float w[2]; float sm = 0.f;
            for (int k = 0; k < c; ++k) { w[k] = __expf(sS[ql][hh][k] - mx); sm += w[k]; }
            float inv = 1.f / sm;
            for (int k = 0; k < c; ++k) sS[ql][hh][k] = w[k] * inv;
        }
        __syncthreads();
        for (int qq = tid >> 6; qq < E_; qq += 4) {
            float4 acc = make_float4(0.f, 0.f, 0.f, 0.f);
#pragma unroll
            for (int hh = 0; hh < H_; ++hh)
                for (int k = 0; k < c; ++k) {
                    float w = sS[qq][hh][k];
                    float4 v = *(const float4*)&sVW[k][hh * D_ + dq * 4];
                    acc.x += w * v.x; acc.y += w * v.y; acc.z += w * v.z; acc.w += w * v.w;
                }
            int row = z ? (qq * E_ + me) : (me * E_ + qq);
            *(float4*)&out[((size_t)b * OUTROWS + baserow + row) * D_ + dq * 4] = acc;
        }
    } else if (c == 0) {
        // fully masked -> uniform softmax over all M mentions
        float s = 0.f;
        for (int m = 0; m < M_; ++m)
            for (int hh = 0; hh < H_; ++hh)
                s += bf2f((unsigned short)VW[((size_t)b * M_ + m) * (H_ * D_) + hh * D_ + tid]);
        sVW[0][tid] = s * (1.0f / M_);
        __syncthreads();
        for (int qq = tid >> 6; qq < E_; qq += 4) {
            float4 v = *(const float4*)&sVW[0][dq * 4];
            int row = z ? (qq * E_ + me) : (me * E_ + qq);
            *(float4*)&out[((size_t)b * OUTROWS + baserow + row) * D_ + dq * 4] = v;
        }
    } else {
        // general fallback (correctness parachute)
        {
            int hh = tid & 3, ql = tid >> 2;
            const float* erow = ents + (size_t)ql * D_;
            float mx = -1e30f;
            for (int k = 0; k < c; ++k) {
                const short* KQrow = KQb + ((size_t)(z * 4 + hh)) * (B_ * M_ * D_)
                                         + ((size_t)b * M_ + lst[k]) * D_;
                mx = fmaxf(mx, dot256_f_bf(erow, KQrow) * 0.125f);
            }
            float sm = 0.f;
            for (int k = 0; k < c; ++k) {
                const short* KQrow = KQb + ((size_t)(z * 4 + hh)) * (B_ * M_ * D_)
                                         + ((size_t)b * M_ + lst[k]) * D_;
                sm += __expf(dot256_f_bf(erow, KQrow) * 0.125f - mx);
            }
            sS[ql][hh][0] = mx;
            sS[ql][hh][1] = sm;
        }
        __syncthreads();
        for (int qq = tid >> 6; qq < E_; qq += 4) {
            float4 acc = make_float4(0.f, 0.f, 0.f, 0.f);
            const float* erow = ents + (size_t)qq * D_;
            for (int hh = 0; hh < H_; ++hh) {
                float mx = sS[qq][hh][0], inv = 1.f / sS[qq][hh][1];
                for (int k = 0; k < c; ++k) {
                    const short* KQrow = KQb + ((size_t)(z * 4 + hh)) * (B_ * M_ * D_)
                                             + ((size_t)b * M_ + lst[k]) * D_;
                    float w = __expf(dot256_f_bf(erow, KQrow) * 0.125f - mx) * inv;
                    ushort4 v4 = *(const ushort4*)(VW + ((size_t)b * M_ + lst[k]) * (H_ * D_) + hh * D_ + dq * 4);
                    acc.x += w * bf2f(v4.x); acc.y += w * bf2f(v4.y);
                    acc.z += w * bf2f(v4.z); acc.w += w * bf2f(v4.w);
                }
            }
            int row = z ? (qq * E_ + me) : (me * E_ + qq);
            *(float4*)&out[((size_t)b * OUTROWS + baserow + row) * D_ + dq * 4] = acc;
        }
    }
}

extern "C" void kernel_launch(void* const* d_in, const int* in_sizes, int n_in,
                              void* d_out, int out_size, void* d_ws, size_t ws_size,
                              hipStream_t stream) {
    const float* nodes     = (const float*)d_in[0];
    const float* adj       = (const float*)d_in[1];
    const float* mentions  = (const float*)d_in[2];
    const float* sentences = (const float*)d_in[3];
    const float* Wr0 = (const float*)d_in[4];
    const float* br0 = (const float*)d_in[5];
    const float* Wr1 = (const float*)d_in[6];
    const float* br1 = (const float*)d_in[7];
    const float* W00 = (const float*)d_in[8];
    const float* b00 = (const float*)d_in[9];
    const float* W01 = (const float*)d_in[10];
    const float* b01 = (const float*)d_in[11];
    const float* Wq_h = (const float*)d_in[12];
    const float* Wk_h = (const float*)d_in[13];
    const float* Wv_h = (const float*)d_in[14];
    const float* Wo_h = (const float*)d_in[15];
    const float* Wq_t = (const float*)d_in[16];
    const float* Wk_t = (const float*)d_in[17];
    const float* Wv_t = (const float*)d_in[18];
    const float* Wo_t = (const float*)d_in[19];
    const int* info_eid = (const int*)d_in[20];
    const int* info_sid = (const int*)d_in[21];
    float* out  = (float*)d_out;
    float* pool = (float*)d_ws;

    // ---- workspace layout (float offsets; shorts noted) ----
    short* xWb   = (short*)pool;                    // [6][1792][256] sh
    short* hb    = (short*)(pool + 1376256);        // [1792][256] sh
    short* KVb   = (short*)(pool + 1671168);        // [Kh,Kt,Vh,Vt] sh
    short* nodesb= (short*)(pool + 2195456);        // [1792][320] sh
    short* msrb  = (short*)(pool + 2482176);        // [1024][256] sh
    short* mentb = (short*)(pool + 2613248);        // [1024][256] sh (adjacent to msrb)
    short* Wb    = (short*)(pool + 2744320);        // 1,802,240 sh
    int*   elist = (int*)(pool + 3645440);          // 344,064
    float* evals = pool + 3989504;                  // 344,064
    int*   ecnt  = (int*)(pool + 4333568);
    float* den   = pool + 4335360;
    int*   mcnt  = (int*)(pool + 4337152);
    int*   mlist = (int*)(pool + 4337664);          // 65,536 fl
    short* VWb   = (short*)(pool + 4403200);        // [2][1024][1024] sh = 1,048,576 fl
    short* KQb   = (short*)(pool + 5451776);        // [8][1024][256] sh = 1,048,576 fl
    short* WQs   = (short*)(pool + 6500352);        // [2][256][256] sh = 65,536 fl
    // total: 6,565,888 fl (~26.3 MB)

    short* W1t = Wb;                 // [6][256][320]
    short* W2t = Wb + 491520;        // [6][256][256]
    short* WKt = Wb + 884736;        // [Wkh, Wkt]
    short* WVt = Wb + 1146880;       // [Wvh, Wvt]
    short* WOt = Wb + 1671168;       // [8][256][64]

    // 1. fused preprocessing
    mega_pre<<<PRE_TOT, 256, 0, stream>>>(
        Wb, Wr0, W00, Wr1, W01, Wk_h, Wk_t, Wv_h, Wv_t, Wq_h, Wq_t, Wo_h, Wo_t,
        adj, ecnt, elist, evals, den, info_eid, mcnt, mlist,
        nodes, mentions, sentences, info_sid, nodesb, mentb, msrb, WQs);

    // 2. GEMM A: z 0..5 = L1 (nodes @ Wr0/W00), z 6..9 = K/V projections
    {
        GTable T = {};
        for (int z = 0; z < 6; ++z)
            T.d[z] = { nodesb, W1t + z * 81920, xWb + (size_t)z * BN_ * D_,
                       (z < 5) ? br0 + z * D_ : b00, 320, 320, D_, 320, 28 };
        for (int zp = 0; zp < 4; ++zp) {
            int half = zp >> 1, wt = zp & 1;  // half: 0=K(msrb,WKt), 1=V(mentb,WVt)
            T.d[6 + zp] = { msrb + half * 262144, (half ? WVt : WKt) + wt * 65536,
                            KVb + half * 524288 + wt * 262144,
                            nullptr, D_, D_, D_, D_, 16 };
        }
        gemm_multi<<<dim3(4, 28, 10), 256, 0, stream>>>(T);
    }
    // 3. AxW layer 1 -> hb (bf16)
    axw_gather<<<BN_, 256, 0, stream>>>(xWb, ecnt, elist, evals, den,
                                        hb, nullptr, 0);
    // 4. GEMM B: z 0..5 = L2 (h @ Wr1/W01) -> xWb, z 6..13 = VW (V @ Wo per head),
    //    z 14..21 = KQ (K_headslice @ Wq_headslice^T) -> folds Q projection away.
    {
        GTable T = {};
        for (int z = 0; z < 6; ++z)
            T.d[z] = { hb, W2t + z * 65536, xWb + (size_t)z * BN_ * D_,
                       (z < 5) ? br1 + z * D_ : b01, D_, D_, D_, D_, 28 };
        for (int zp = 0; zp < 8; ++zp) {
            int which = zp >> 2, hh = zp & 3;
            T.d[6 + zp] = { KVb + 524288 + which * 262144 + hh * DK_,
                            WOt + which * 65536 + hh * 16384,
                            VWb + (size_t)which * (B_ * M_ * H_ * D_) + hh * D_,
                            nullptr, D_, DK_, H_ * D_, DK_, 16 };
        }
        for (int zp = 0; zp < 8; ++zp) {
            int which = zp >> 2, hh = zp & 3;
            T.d[14 + zp] = { KVb + which * 262144 + hh * DK_,          // K head slice
                             WQs + which * 65536 + hh * DK_,           // Wq rows, head cols
                             KQb + (size_t)(which * 4 + hh) * (B_ * M_ * D_),
                             nullptr, D_, D_, D_, DK_, 16 };
        }
        gemm_multi<<<dim3(4, 28, 22), 256, 0, stream>>>(T);
    }
    // 5. AxW layer 2 -> gcn_out (fp32 first N rows of out per batch)
    axw_gather<<<BN_, 256, 0, stream>>>(xWb, ecnt, elist, evals, den,
                                        nullptr, out, (long long)OUTROWS * D_);
    // 6. merged attention combine: 1D grid, XCD-grouped (b,z) decode
    combine_kernel<<<E_ * B_ * 2, 256, 0, stream>>>(KQb, VWb, mcnt, mlist, out);
}

// Round 15
// 91.581 us; speedup vs baseline: 1.5961x; 1.5961x over previous
//
#include <hip/hip_runtime.h>
#include <math.h>

#define B_ 8
#define N_ 224
#define E_ 64
#define M_ 128
#define S_ 32
#define D_ 256
#define IN_ 300
#define R_ 5
#define H_ 4
#define DK_ 64
#define OUTROWS (N_ + 2 * E_ * E_)   // 8416
#define CAP_ 192
#define BN_ (B_ * N_)                // 1792

typedef __attribute__((ext_vector_type(8))) short bf16x8;
typedef __attribute__((ext_vector_type(8))) unsigned short u16x8;
typedef __attribute__((ext_vector_type(4))) float f32x4;

__device__ inline short f2bf(float f) {
    union { float f; unsigned u; } x; x.f = f;
    unsigned u = x.u;
    unsigned r = (u + 0x7fffu + ((u >> 16) & 1u)) >> 16;
    return (short)r;
}
__device__ inline float bf2f(unsigned short s) {
    union { unsigned u; float f; } x; x.u = ((unsigned)s) << 16; return x.f;
}

// async global -> LDS, 16B per lane; lds base must be wave-uniform
__device__ inline void gload16(const void* g, void* l) {
    __builtin_amdgcn_global_load_lds(
        (const __attribute__((address_space(1))) unsigned int*)g,
        (__attribute__((address_space(3))) unsigned int*)l, 16, 0, 0);
}

// ================= mega preprocessing kernel (block-range dispatch) =================
#define PRE_PACK 1376
#define PRE_EDGE (PRE_PACK + BN_)     // 3168
#define PRE_ML   (PRE_EDGE + 2)       // 3170
#define CVT_N    573440               // 1792*320
#define CVT_M    262144               // 1024*256
#define PRE_TOT  (PRE_ML + 1072)

__global__ __launch_bounds__(256) void mega_pre(
    short* __restrict__ Wb,
    const float* Wr0, const float* W00, const float* Wr1, const float* W01,
    const float* Wkh, const float* Wkt, const float* Wvh, const float* Wvt,
    const float* Wqh, const float* Wqt, const float* Woh, const float* Wot,
    const float* __restrict__ adj, int* __restrict__ ecnt, int* __restrict__ elist,
    float* __restrict__ evals, float* __restrict__ den,
    const int* __restrict__ eid, int* __restrict__ mcnt, int* __restrict__ mlist,
    const float* __restrict__ nodes, const float* __restrict__ mentions,
    const float* __restrict__ sentences, const int* __restrict__ sid,
    short* __restrict__ nodesb, short* __restrict__ mentb, short* __restrict__ msrb) {
    __shared__ int smemi[528];
    __shared__ int wtot[4];
    __shared__ float wsum[4];
    int blk = blockIdx.x, tid = threadIdx.x;

    if (blk < PRE_PACK) {
        // ---- weight pack: bf16 transposed [n][k], 32x32 LDS transpose ----
        short (*T)[33] = (short(*)[33])smemi;
        int t = blk;
        const float* src; short* outp; int outld, klim, n0, k0;
        if (t < 480) {
            int z = t / 80, tt = t % 80;
            n0 = (tt & 7) * 32; k0 = (tt >> 3) * 32;
            outp = Wb + (size_t)z * 81920; outld = 320; klim = IN_;
            src = (z < 5) ? Wr0 + (size_t)z * IN_ * D_ : W00;
        } else if (t < 864) {
            int l = t - 480, z = l / 64, tt = l % 64;
            n0 = (tt & 7) * 32; k0 = (tt >> 3) * 32;
            outp = Wb + 491520 + (size_t)z * 65536; outld = 256; klim = 256;
            src = (z < 5) ? Wr1 + (size_t)z * D_ * D_ : W01;
        } else if (t < 992) {
            int l = t - 864, z = l / 64, tt = l % 64;
            n0 = (tt & 7) * 32; k0 = (tt >> 3) * 32;
            outp = Wb + 884736 + (size_t)z * 65536; outld = 256; klim = 256;
            src = z ? Wkt : Wkh;
        } else if (t < 1120) {
            int l = t - 992, z = l / 64, tt = l % 64;
            n0 = (tt & 7) * 32; k0 = (tt >> 3) * 32;
            outp = Wb + 1146880 + (size_t)z * 65536; outld = 256; klim = 256;
            src = z ? Wvt : Wvh;
        } else if (t < 1248) {
            int l = t - 1120, z = l / 64, tt = l % 64;
            n0 = (tt & 7) * 32; k0 = (tt >> 3) * 32;
            outp = Wb + 1409024 + (size_t)z * 65536; outld = 256; klim = 256;
            src = z ? Wqt : Wqh;
        } else {
            int l = t - 1248, z = l / 16, tt = l % 16;
            n0 = (tt & 7) * 32; k0 = (tt >> 3) * 32;
            outp = Wb + 1671168 + (size_t)z * 16384; outld = 64; klim = 64;
            int which = z >> 2, h = z & 3;
            src = (which ? Wot : Woh) + (size_t)(h * 64) * D_;
        }
        int tx = tid & 31, ty = tid >> 5;
#pragma unroll
        for (int i = 0; i < 4; ++i) {
            int k = k0 + ty + 8 * i;
            float v = (k < klim) ? src[(size_t)k * D_ + n0 + tx] : 0.f;
            T[tx][ty + 8 * i] = f2bf(v);
        }
        __syncthreads();
#pragma unroll
        for (int i = 0; i < 4; ++i) {
            int n = ty + 8 * i;
            outp[(size_t)(n0 + n) * outld + k0 + tx] = T[n][tx];
        }
    } else if (blk < PRE_EDGE) {
        // ---- edge lists + denoms: shfl-scan; XCD-swizzled so batch b -> one XCD ----
        int local = blk - PRE_PACK;
        int bn = (local & 7) * N_ + (local >> 3);   // b = local%8 pinned per XCD
        int b = bn / N_, n = bn % N_;
        int lane = tid & 63, wv4 = tid >> 6;
        int idxs[5]; float vals[5];
        int cloc = 0; float sloc = 0.f;
        for (int e = tid; e < R_ * N_; e += 256) {
            int r = e / N_, m = e % N_;
            float v = adj[(((size_t)(b * R_ + r)) * N_ + n) * N_ + m];
            if (v != 0.f) { idxs[cloc] = r * BN_ + m; vals[cloc] = v; ++cloc; sloc += v; }
        }
        int v = cloc;
#pragma unroll
        for (int st = 1; st < 64; st <<= 1) {
            int o = __shfl_up(v, st, 64);
            if (lane >= st) v += o;
        }
        float fs = sloc;
#pragma unroll
        for (int st = 32; st > 0; st >>= 1) fs += __shfl_xor(fs, st, 64);
        if (lane == 63) wtot[wv4] = v;
        if (lane == 0)  wsum[wv4] = fs;
        __syncthreads();
        int woff = 0;
        for (int i = 0; i < wv4; ++i) woff += wtot[i];
        int off = woff + v - cloc;
        int total = wtot[0] + wtot[1] + wtot[2] + wtot[3];
        size_t base = (size_t)bn * CAP_;
        for (int i = 0; i < cloc; ++i) {
            int p = off + i;
            if (p < CAP_) { elist[base + p] = idxs[i]; evals[base + p] = vals[i]; }
        }
        if (tid == 0) {
            ecnt[bn] = total < CAP_ ? total : CAP_;
            den[bn] = wsum[0] + wsum[1] + wsum[2] + wsum[3] + 1.0f;
        }
    } else if (blk < PRE_ML) {
        int t = (blk - PRE_EDGE) * 256 + tid;
        if (t < B_ * E_) {
            int b = t / E_, i = t % E_;
            int c = 0;
            for (int m = 0; m < M_; ++m)
                if (eid[b * M_ + m] == i) mlist[(size_t)t * M_ + c++] = m;
            mcnt[t] = c;
        }
    } else {
        int idx = (blk - PRE_ML) * 1024 + tid * 4;
#pragma unroll
        for (int j = 0; j < 4; ++j) {
            int i = idx + j;
            if (i < CVT_N) {
                int row = i / 320, k = i % 320;
                nodesb[i] = (k < IN_) ? f2bf(nodes[(size_t)row * IN_ + k]) : (short)0;
            } else if (i < CVT_N + CVT_M) {
                int i2 = i - CVT_N;
                mentb[i2] = f2bf(mentions[i2]);
            } else {
                int i3 = i - CVT_N - CVT_M;
                int bm = i3 >> 8, d = i3 & 255;
                msrb[i3] = f2bf(sentences[(size_t)sid[bm] * D_ + d]);
            }
        }
    }
}

// ---------- AxW via edge gather (bf16 xW), 4 gather-waves + LDS reduce ----------
// XCD-swizzled: bn = (bid%8)*N + bid/8 pins batch b to one XCD (per-XCD
// working set ~0.7 MB << 4 MB L2).  elist stores r*BN+m directly.
__global__ __launch_bounds__(256) void axw_gather(
    const short* __restrict__ xWb,
    const int* __restrict__ ecnt, const int* __restrict__ elist,
    const float* __restrict__ evals, const float* __restrict__ den,
    short* __restrict__ hb, float* __restrict__ out, long long out_bstride,
    short* __restrict__ entsb) {
    int bid = blockIdx.x;
    int bn = (bid & 7) * N_ + (bid >> 3);
    int b = bn / N_, n = bn % N_;
    int tid = threadIdx.x, wv = tid >> 6, dq = tid & 63;
    int c = ecnt[bn];
    int bno = b * N_;
    const int* lst = elist + (size_t)bn * CAP_;
    const float* vls = evals + (size_t)bn * CAP_;
    float4 acc = make_float4(0.f, 0.f, 0.f, 0.f);
#pragma unroll 2
    for (int k = wv; k < c; k += 4) {
        int rm = lst[k];
        float v = vls[k];
        ushort4 x4 = *(const ushort4*)&xWb[((size_t)(rm + bno)) * 256 + dq * 4];
        acc.x += v * bf2f(x4.x); acc.y += v * bf2f(x4.y);
        acc.z += v * bf2f(x4.z); acc.w += v * bf2f(x4.w);
    }
    __shared__ float4 red[4][64];
    red[wv][dq] = acc;
    __syncthreads();
    if (tid < 64) {
        float4 s0 = red[0][dq], s1 = red[1][dq], s2 = red[2][dq], s3 = red[3][dq];
        ushort4 t4 = *(const ushort4*)&xWb[((size_t)(5 * BN_ + bn)) * 256 + dq * 4];
        float inv = 1.f / den[bn];
        float4 o;
        o.x = fmaxf((s0.x + s1.x + s2.x + s3.x + bf2f(t4.x)) * inv, 0.f);
        o.y = fmaxf((s0.y + s1.y + s2.y + s3.y + bf2f(t4.y)) * inv, 0.f);
        o.z = fmaxf((s0.z + s1.z + s2.z + s3.z + bf2f(t4.z)) * inv, 0.f);
        o.w = fmaxf((s0.w + s1.w + s2.w + s3.w + bf2f(t4.w)) * inv, 0.f);
        if (hb) {
            ushort4 hw = { (unsigned short)f2bf(o.x), (unsigned short)f2bf(o.y),
                           (unsigned short)f2bf(o.z), (unsigned short)f2bf(o.w) };
            *(ushort4*)&hb[(size_t)bn * 256 + dq * 4] = hw;
        }
        if (out)
            *(float4*)&out[(size_t)b * out_bstride + (size_t)n * 256 + dq * 4] = o;
        if (entsb && n < E_) {
            ushort4 ew = { (unsigned short)f2bf(o.x), (unsigned short)f2bf(o.y),
                           (unsigned short)f2bf(o.z), (unsigned short)f2bf(o.w) };
            *(ushort4*)&entsb[((size_t)b * E_ + n) * 256 + dq * 4] = ew;
        }
    }
}

// ---------- multi-GEMM: per-blockIdx.z descriptor, all-bf16, tile 64x64, BK=64 ----------
struct GDesc {
    const short* A; const short* Bt; short* C; const float* bias;
    int lda, ldbk, ldc, Kloop, ny;
};
struct GTable { GDesc d[14]; };

__global__ __launch_bounds__(256) void gemm_multi(GTable T) {
    GDesc g = T.d[blockIdx.z];
    if ((int)blockIdx.y >= g.ny) return;

    __shared__ short As[64 * 64];
    __shared__ short Bs[64 * 64];
    int tid = threadIdx.x;
    int lane = tid & 63, wv = tid >> 6;
    int wr = wv >> 1, wc = wv & 1;
    int fr = lane & 15;
    int so = lane >> 4;              // fragment slot sub-index (0..3)
    int row0 = blockIdx.y * 64, col0 = blockIdx.x * 64;

    // staging geometry: each wave stages chunks c0,c1 (1KB each = 8 rows x 128B)
    int l8 = lane >> 3;              // row within chunk (0..7)
    int sl = (lane & 7) ^ l8;        // pre-swizzled 16B slot
    int c0 = 2 * wv, c1 = c0 + 1;
    int ra0 = row0 + 8 * c0 + l8, ra1 = row0 + 8 * c1 + l8;
    int rb0 = col0 + 8 * c0 + l8, rb1 = col0 + 8 * c1 + l8;

    f32x4 acc00 = {0.f,0.f,0.f,0.f}, acc01 = acc00, acc10 = acc00, acc11 = acc00;

    int rA0 = wr * 32 + fr, rA1 = rA0 + 16;
    int rB0 = wc * 32 + fr, rB1 = rB0 + 16;
    int sw = fr & 7;

    for (int k0 = 0; k0 < g.Kloop; k0 += 64) {
        gload16(&g.A [(size_t)ra0 * g.lda  + k0 + sl * 8], &As[c0 * 512]);
        gload16(&g.A [(size_t)ra1 * g.lda  + k0 + sl * 8], &As[c1 * 512]);
        gload16(&g.Bt[(size_t)rb0 * g.ldbk + k0 + sl * 8], &Bs[c0 * 512]);
        gload16(&g.Bt[(size_t)rb1 * g.ldbk + k0 + sl * 8], &Bs[c1 * 512]);
        __syncthreads();
#pragma unroll
        for (int ks = 0; ks < 2; ++ks) {
            int s = ks * 4 + so;
            bf16x8 a0 = *(bf16x8*)&As[rA0 * 64 + ((s ^ sw) << 3)];
            bf16x8 a1 = *(bf16x8*)&As[rA1 * 64 + ((s ^ sw) << 3)];
            bf16x8 b0 = *(bf16x8*)&Bs[rB0 * 64 + ((s ^ sw) << 3)];
            bf16x8 b1 = *(bf16x8*)&Bs[rB1 * 64 + ((s ^ sw) << 3)];
            acc00 = __builtin_amdgcn_mfma_f32_16x16x32_bf16(a0, b0, acc00, 0, 0, 0);
            acc01 = __builtin_amdgcn_mfma_f32_16x16x32_bf16(a0, b1, acc01, 0, 0, 0);
            acc10 = __builtin_amdgcn_mfma_f32_16x16x32_bf16(a1, b0, acc10, 0, 0, 0);
            acc11 = __builtin_amdgcn_mfma_f32_16x16x32_bf16(a1, b1, acc11, 0, 0, 0);
        }
        __syncthreads();
    }

    int rbase = row0 + wr * 32 + (lane >> 4) * 4;
    int cbase = col0 + wc * 32 + fr;
    f32x4 accs[2][2] = {{acc00, acc01}, {acc10, acc11}};
#pragma unroll
    for (int mi = 0; mi < 2; ++mi) {
#pragma unroll
        for (int nj = 0; nj < 2; ++nj) {
            int cc = cbase + nj * 16;
            float bval = g.bias ? g.bias[cc] : 0.f;
#pragma unroll
            for (int r = 0; r < 4; ++r) {
                int cr = rbase + mi * 16 + r;
                g.C[(size_t)cr * g.ldc + cc] = f2bf(accs[mi][nj][r] + bval);
            }
        }
    }
}

__device__ inline float dot64_bf(const short* q, const short* k) {
    float dot = 0.f;
#pragma unroll
    for (int t8 = 0; t8 < 8; ++t8) {
        u16x8 qv = *(const u16x8*)(q + t8 * 8);
        u16x8 kv = *(const u16x8*)(k + t8 * 8);
#pragma unroll
        for (int j = 0; j < 8; ++j) dot += bf2f(qv[j]) * bf2f(kv[j]);
    }
    return dot;
}

// ------------- per (b, masked-entity, rep) attention combine: 64 q rows/block -------------
// 1D grid 1024, XCD-swizzled decode: g = bid%16 (g = z*8+b), me = bid/16 —
// all 64 me-blocks of one (b,z) group share an XCD (K/Q/VW ~350 KB L2-local).
__global__ __launch_bounds__(256) void combine_kernel(
    const short* __restrict__ Qb, const short* __restrict__ Kb,
    const short* __restrict__ VWb, const int* __restrict__ cnt,
    const int* __restrict__ mlist, float* __restrict__ out) {
    int bid = blockIdx.x;
    int g = bid & 15, me = bid >> 4;
    int b = g & 7, z = g >> 3;
    const short* Q  = Qb  + (size_t)z * (B_ * E_ * D_);
    const short* K  = Kb  + (size_t)z * (B_ * M_ * D_);
    const short* VW = VWb + (size_t)z * (B_ * M_ * H_ * D_);
    int baserow = N_ + z * (E_ * E_);
    int tid = threadIdx.x;
    int dq = tid & 63;
    __shared__ float sVW[2][H_ * D_];
    __shared__ float sS[E_][H_][2];
    int c = cnt[b * E_ + me];
    const int* lst = mlist + (size_t)(b * E_ + me) * M_;

    if (c >= 1 && c <= 2) {
        for (int k = 0; k < c; ++k) {
            ushort4 v4 = *(const ushort4*)(VW + ((size_t)b * M_ + lst[k]) * (H_ * D_) + tid * 4);
            *(float4*)&sVW[k][tid * 4] =
                make_float4(bf2f(v4.x), bf2f(v4.y), bf2f(v4.z), bf2f(v4.w));
        }
        for (int e = tid; e < E_ * H_ * 2; e += 256) {
            int k = e & 1, hh = (e >> 1) & 3, ql = e >> 3;
            if (k < c) {
                const short* Qrow = Q + ((size_t)b * E_ + ql) * D_ + hh * DK_;
                const short* Krow = K + ((size_t)b * M_ + lst[k]) * D_ + hh * DK_;
                sS[ql][hh][k] = dot64_bf(Qrow, Krow) * 0.125f;
            }
        }
        __syncthreads();
        {   // softmax: one (ql,hh) per thread (256 = 64*4)
            int hh = tid & 3, ql = tid >> 2;
            float mx = sS[ql][hh][0];
            for (int k = 1; k < c; ++k) mx = fmaxf(mx, sS[ql][hh][k]);
            float w[2]; float sm = 0.f;
            for (int k = 0; k < c; ++k) { w[k] = __expf(sS[ql][hh][k] - mx); sm += w[k]; }
            float inv = 1.f / sm;
            for (int k = 0; k < c; ++k) sS[ql][hh][k] = w[k] * inv;
        }
        __syncthreads();
        for (int qq = tid >> 6; qq < E_; qq += 4) {
            float4 acc = make_float4(0.f, 0.f, 0.f, 0.f);
#pragma unroll
            for (int hh = 0; hh < H_; ++hh)
                for (int k = 0; k < c; ++k) {
                    float w = sS[qq][hh][k];
                    float4 v = *(const float4*)&sVW[k][hh * D_ + dq * 4];
                    acc.x += w * v.x; acc.y += w * v.y; acc.z += w * v.z; acc.w += w * v.w;
                }
            int row = z ? (qq * E_ + me) : (me * E_ + qq);
            *(float4*)&out[((size_t)b * OUTROWS + baserow + row) * D_ + dq * 4] = acc;
        }
    } else if (c == 0) {
        // fully masked -> uniform softmax over all M mentions
        float s = 0.f;
        for (int m = 0; m < M_; ++m)
            for (int hh = 0; hh < H_; ++hh)
                s += bf2f((unsigned short)VW[((size_t)b * M_ + m) * (H_ * D_) + hh * D_ + tid]);
        sVW[0][tid] = s * (1.0f / M_);
        __syncthreads();
        for (int qq = tid >> 6; qq < E_; qq += 4) {
            float4 v = *(const float4*)&sVW[0][dq * 4];
            int row = z ? (qq * E_ + me) : (me * E_ + qq);
            *(float4*)&out[((size_t)b * OUTROWS + baserow + row) * D_ + dq * 4] = v;
        }
    } else {
        // general fallback (correctness parachute)
        {
            int hh = tid & 3, ql = tid >> 2;
            const short* Qrow = Q + ((size_t)b * E_ + ql) * D_ + hh * DK_;
            float mx = -1e30f;
            for (int k = 0; k < c; ++k) {
                const short* Krow = K + ((size_t)b * M_ + lst[k]) * D_ + hh * DK_;
                mx = fmaxf(mx, dot64_bf(Qrow, Krow) * 0.125f);
            }
            float sm = 0.f;
            for (int k = 0; k < c; ++k) {
                const short* Krow = K + ((size_t)b * M_ + lst[k]) * D_ + hh * DK_;
                sm += __expf(dot64_bf(Qrow, Krow) * 0.125f - mx);
            }
            sS[ql][hh][0] = mx;
            sS[ql][hh][1] = sm;
        }
        __syncthreads();
        for (int qq = tid >> 6; qq < E_; qq += 4) {
            float4 acc = make_float4(0.f, 0.f, 0.f, 0.f);
            for (int hh = 0; hh < H_; ++hh) {
                float mx = sS[qq][hh][0], inv = 1.f / sS[qq][hh][1];
                const short* Qrow = Q + ((size_t)b * E_ + qq) * D_ + hh * DK_;
                for (int k = 0; k < c; ++k) {
                    const short* Krow = K + ((size_t)b * M_ + lst[k]) * D_ + hh * DK_;
                    float w = __expf(dot64_bf(Qrow, Krow) * 0.125f - mx) * inv;
                    ushort4 v4 = *(const ushort4*)(VW + ((size_t)b * M_ + lst[k]) * (H_ * D_) + hh * D_ + dq * 4);
                    acc.x += w * bf2f(v4.x); acc.y += w * bf2f(v4.y);
                    acc.z += w * bf2f(v4.z); acc.w += w * bf2f(v4.w);
                }
            }
            int row = z ? (qq * E_ + me) : (me * E_ + qq);
            *(float4*)&out[((size_t)b * OUTROWS + baserow + row) * D_ + dq * 4] = acc;
        }
    }
}

extern "C" void kernel_launch(void* const* d_in, const int* in_sizes, int n_in,
                              void* d_out, int out_size, void* d_ws, size_t ws_size,
                              hipStream_t stream) {
    const float* nodes     = (const float*)d_in[0];
    const float* adj       = (const float*)d_in[1];
    const float* mentions  = (const float*)d_in[2];
    const float* sentences = (const float*)d_in[3];
    const float* Wr0 = (const float*)d_in[4];
    const float* br0 = (const float*)d_in[5];
    const float* Wr1 = (const float*)d_in[6];
    const float* br1 = (const float*)d_in[7];
    const float* W00 = (const float*)d_in[8];
    const float* b00 = (const float*)d_in[9];
    const float* W01 = (const float*)d_in[10];
    const float* b01 = (const float*)d_in[11];
    const float* Wq_h = (const float*)d_in[12];
    const float* Wk_h = (const float*)d_in[13];
    const float* Wv_h = (const float*)d_in[14];
    const float* Wo_h = (const float*)d_in[15];
    const float* Wq_t = (const float*)d_in[16];
    const float* Wk_t = (const float*)d_in[17];
    const float* Wv_t = (const float*)d_in[18];
    const float* Wo_t = (const float*)d_in[19];
    const int* info_eid = (const int*)d_in[20];
    const int* info_sid = (const int*)d_in[21];
    float* out  = (float*)d_out;
    float* pool = (float*)d_ws;

    // ---- workspace layout (float offsets; shorts noted) ----
    short* xWb   = (short*)pool;                    // [6][1792][256] sh
    short* hb    = (short*)(pool + 1376256);        // [1792][256] sh
    short* entsb = (short*)(pool + 1605632);        // [8][64][256] sh
    short* KVb   = (short*)(pool + 1671168);        // [Kh,Kt,Vh,Vt] sh
    short* nodesb= (short*)(pool + 2195456);        // [1792][320] sh
    short* msrb  = (short*)(pool + 2482176);        // [1024][256] sh
    short* mentb = (short*)(pool + 2613248);        // [1024][256] sh (adjacent to msrb)
    short* Wb    = (short*)(pool + 2744320);        // 1,802,240 sh
    int*   elist = (int*)(pool + 3645440);          // 344,064
    float* evals = pool + 3989504;                  // 344,064
    int*   ecnt  = (int*)(pool + 4333568);
    float* den   = pool + 4335360;
    int*   mcnt  = (int*)(pool + 4337152);
    int*   mlist = (int*)(pool + 4337664);          // 65,536 fl
    short* VWb   = (short*)(pool + 4403200);        // [2][1024][1024] sh = 1,048,576 fl
    short* Qb    = (short*)(pool + 5451776);        // [2][8][64][256] sh = 131,072 fl
    // total: 5,582,848 fl (~22.3 MB)

    short* W1t = Wb;                 // [6][256][320]
    short* W2t = Wb + 491520;        // [6][256][256]
    short* WKt = Wb + 884736;        // [Wkh, Wkt]
    short* WVt = Wb + 1146880;       // [Wvh, Wvt]
    short* WQt = Wb + 1409024;       // [Wqh, Wqt]
    short* WOt = Wb + 1671168;       // [8][256][64]

    // 1. fused preprocessing
    mega_pre<<<PRE_TOT, 256, 0, stream>>>(
        Wb, Wr0, W00, Wr1, W01, Wk_h, Wk_t, Wv_h, Wv_t, Wq_h, Wq_t, Wo_h, Wo_t,
        adj, ecnt, elist, evals, den, info_eid, mcnt, mlist,
        nodes, mentions, sentences, info_sid, nodesb, mentb, msrb);

    // 2. GEMM A: z 0..5 = L1 (nodes @ Wr0/W00), z 6..9 = K/V projections
    {
        GTable T = {};
        for (int z = 0; z < 6; ++z)
            T.d[z] = { nodesb, W1t + z * 81920, xWb + (size_t)z * BN_ * D_,
                       (z < 5) ? br0 + z * D_ : b00, 320, 320, D_, 320, 28 };
        for (int zp = 0; zp < 4; ++zp) {
            int half = zp >> 1, wt = zp & 1;  // half: 0=K(msrb,WKt), 1=V(mentb,WVt)
            T.d[6 + zp] = { msrb + half * 262144, (half ? WVt : WKt) + wt * 65536,
                            KVb + half * 524288 + wt * 262144,
                            nullptr, D_, D_, D_, D_, 16 };
        }
        gemm_multi<<<dim3(4, 28, 10), 256, 0, stream>>>(T);
    }
    // 3. AxW layer 1 -> hb (bf16)
    axw_gather<<<BN_, 256, 0, stream>>>(xWb, ecnt, elist, evals, den,
                                        hb, nullptr, 0, nullptr);
    // 4. GEMM B: z 0..5 = L2 (h @ Wr1/W01) -> xWb, z 6..13 = VW (V @ Wo per head)
    {
        GTable T = {};
        for (int z = 0; z < 6; ++z)
            T.d[z] = { hb, W2t + z * 65536, xWb + (size_t)z * BN_ * D_,
                       (z < 5) ? br1 + z * D_ : b01, D_, D_, D_, D_, 28 };
        for (int zp = 0; zp < 8; ++zp) {
            int which = zp >> 2, hh = zp & 3;
            T.d[6 + zp] = { KVb + 524288 + which * 262144 + hh * DK_,
                            WOt + which * 65536 + hh * 16384,
                            VWb + (size_t)which * (B_ * M_ * H_ * D_) + hh * D_,
                            nullptr, D_, DK_, H_ * D_, DK_, 16 };
        }
        gemm_multi<<<dim3(4, 28, 14), 256, 0, stream>>>(T);
    }
    // 5. AxW layer 2 -> gcn_out (fp32 first N rows of out) + entsb (bf16)
    axw_gather<<<BN_, 256, 0, stream>>>(xWb, ecnt, elist, evals, den,
                                        nullptr, out, (long long)OUTROWS * D_, entsb);
    // 6. GEMM C: Q projections only — 2 descriptors, ny=8 (entsb is [8*64][256])
    {
        GTable T = {};
        for (int which = 0; which < 2; ++which)
            T.d[which] = { entsb, WQt + which * 65536, Qb + which * 131072,
                           nullptr, D_, D_, D_, D_, 8 };
        gemm_multi<<<dim3(4, 8, 2), 256, 0, stream>>>(T);
    }
    // 7. merged attention combine: 1D grid, XCD-grouped (b,z) decode
    combine_kernel<<<E_ * B_ * 2, 256, 0, stream>>>(Qb, KVb, VWb, mcnt, mlist, out);
}